// Round 8
// baseline (424.155 us; speedup 1.0000x reference)
//
#include <hip/hip_runtime.h>
#include <hip/hip_bf16.h>

// Mamba block — split-bf16 MFMA GEMMs (32x32x16 + XCD swizzle) + chunked scan.
//  1) xz = x @ W_in.T      (2048x4096, K=2048)  MFMA split-bf16  -> ws.xz (fp32)
//  2) u  = silu(conv4(xz[:, :2048]))            vectorized x4    -> ws.u
//  3) x_dbl = u @ W_xproj.T (2048x160, K=2048)  fp32 split-K(8)  -> ws.xdbl
//  4) dt = softplus(x_dbl[:,:128] @ W_dt.T + b_dt) fp32 VALU     -> ws.dt
//  5) chunked scan (S1/S2/S3), S3 emits yh/yl bf16 planes fused  -> ws.yh/yl
//  6) out = yact @ W_out.T (2048x2048, K=2048)  MFMA split-bf16  -> d_out
//
// Round-8 changes vs round-7 (each independently diagnosable):
//  (a) gemm_bf3 uses v_mfma_f32_32x32x16_bf16 (8.07cyc/32.8KFLOP vs
//      4.85cyc/16.4KFLOP => ~17% fewer MFMA cycles). Same staging/LDS/swizzle.
//  (b) bijective XCD swizzle on gemm_bf3 block ids (nwg%8==0 for both GEMMs).
//  (c) x+W_in splits merged into one dispatch (W_out split stays separate:
//      its destination region aliasing requires it to run after GEMM1).

#define D_MODEL 2048
#define D_STATE 16
#define KER 4
#define DT_RANK 128
#define B_SZ 2
#define SEQ 1024
#define BL (B_SZ * SEQ)
#define XPROJ_N (DT_RANK + 2 * D_STATE)  // 160
#define NC 32
#define TC (SEQ / NC)

using f32x4  = __attribute__((ext_vector_type(4))) float;
using f32x16 = __attribute__((ext_vector_type(16))) float;
using bf16x8 = __attribute__((ext_vector_type(8))) __bf16;
using bf16x4 = __attribute__((ext_vector_type(4))) __bf16;

__device__ __forceinline__ float softplusf(float x) {
    return (x > 20.f) ? x : log1pf(__expf(x));
}
__device__ __forceinline__ float siluf(float x) {
    return x / (1.f + __expf(-x));
}

// ---------------- fp32 -> (hi, lo) bf16 plane split ----------------
__device__ __forceinline__ void split4(const float* __restrict__ src,
                                       __bf16* __restrict__ hi,
                                       __bf16* __restrict__ lo, int i) {
    float4 v = *reinterpret_cast<const float4*>(&src[(size_t)i * 4]);
    bf16x4 hv, lv;
    float f[4] = {v.x, v.y, v.z, v.w};
    #pragma unroll
    for (int j = 0; j < 4; ++j) {
        __bf16 h = (__bf16)f[j];
        hv[j] = h;
        lv[j] = (__bf16)(f[j] - (float)h);
    }
    *reinterpret_cast<bf16x4*>(&hi[(size_t)i * 4]) = hv;
    *reinterpret_cast<bf16x4*>(&lo[(size_t)i * 4]) = lv;
}

__global__ __launch_bounds__(256) void split_kernel(
    const float* __restrict__ src,
    __bf16* __restrict__ hi, __bf16* __restrict__ lo, int n4)
{
    int i = blockIdx.x * 256 + threadIdx.x;
    if (i >= n4) return;
    split4(src, hi, lo, i);
}

// merged x + W_in split (one dispatch), grid-stride
__global__ __launch_bounds__(256) void split_xwi_kernel(
    const float* __restrict__ x,  __bf16* __restrict__ xh,  __bf16* __restrict__ xl,
    const float* __restrict__ wi, __bf16* __restrict__ wih, __bf16* __restrict__ wil)
{
    const int NX = BL * D_MODEL / 4;            // 1,048,576 float4s
    const int NI = 2 * D_MODEL * D_MODEL / 4;   // 2,097,152
    const int total = NX + NI;
    for (int i = blockIdx.x * 256 + threadIdx.x; i < total; i += gridDim.x * 256) {
        if (i < NX) split4(x, xh, xl, i);
        else        split4(wi, wih, wil, i - NX);
    }
}

// ---------------- split-bf16 MFMA NT GEMM (32x32x16) ----------------
// C[m][n] = sum_k A[m,k]*W[n,k], A ~ Ah+Al, W ~ Wh+Wl (drop Al*Wl).
// 128x128 tile, BK=64, 4 waves (2x2 of 64x64), mfma_f32_32x32x16_bf16.
// LDS linear row-major [128][64] bf16 per plane; XOR swizzle slot^=(row&7)
// applied on BOTH global source (pre-swizzle) and ds_read (rule #21).
// A/B frag: row=l&31, k=(l>>5)*8+i. C/D: col=l&31, row=(reg&3)+8*(reg>>2)+4*(l>>5).
__global__ __launch_bounds__(256, 2) void gemm_bf3(
    const __bf16* __restrict__ Ah, const __bf16* __restrict__ Al,
    const __bf16* __restrict__ Wh, const __bf16* __restrict__ Wl,
    float* __restrict__ C, int N_, int K)
{
    __shared__ __align__(16) __bf16 lds[4 * 128 * 64];
    __bf16* sAh = lds;
    __bf16* sAl = lds + 8192;
    __bf16* sWh = lds + 16384;
    __bf16* sWl = lds + 24576;

    const int tid = threadIdx.x;

    // bijective XCD swizzle (both GEMM grids have nwg % 8 == 0)
    const int nwg = gridDim.x * gridDim.y;
    const int fid = blockIdx.y * gridDim.x + blockIdx.x;
    const int nid = (fid & 7) * (nwg >> 3) + (fid >> 3);
    const int bm = (nid / gridDim.x) * 128;
    const int bn = (nid % gridDim.x) * 128;

    const int w  = tid >> 6;
    const int l  = tid & 63;
    const int wr = (w >> 1) * 64;
    const int wc = (w & 1) * 64;
    const int lr = l & 31;     // row/col within 32
    const int kg = l >> 5;     // k-group (0/1): k = kg*8 + i

    f32x16 acc[2][2] = {};

    for (int k0 = 0; k0 < K; k0 += 64) {
        #pragma unroll
        for (int i = 0; i < 4; ++i) {
            const int f  = i * 256 + tid;   // 16B chunk id 0..1023
            const int r  = f >> 3;          // tile row 0..127
            const int ss = f & 7;           // dest slot
            const int gs = ss ^ (r & 7);    // pre-swizzled source slot
            const size_t ga = (size_t)(bm + r) * K + k0 + gs * 8;
            const size_t gw = (size_t)(bn + r) * K + k0 + gs * 8;
            __builtin_amdgcn_global_load_lds(
                (const __attribute__((address_space(1))) void*)(Ah + ga),
                (__attribute__((address_space(3))) void*)(sAh + (size_t)f * 8), 16, 0, 0);
            __builtin_amdgcn_global_load_lds(
                (const __attribute__((address_space(1))) void*)(Al + ga),
                (__attribute__((address_space(3))) void*)(sAl + (size_t)f * 8), 16, 0, 0);
            __builtin_amdgcn_global_load_lds(
                (const __attribute__((address_space(1))) void*)(Wh + gw),
                (__attribute__((address_space(3))) void*)(sWh + (size_t)f * 8), 16, 0, 0);
            __builtin_amdgcn_global_load_lds(
                (const __attribute__((address_space(1))) void*)(Wl + gw),
                (__attribute__((address_space(3))) void*)(sWl + (size_t)f * 8), 16, 0, 0);
        }
        __syncthreads();

        #pragma unroll
        for (int ks = 0; ks < 4; ++ks) {           // k16-step within BK=64
            const int slot = ks * 2 + kg;          // 16B slot holding k=slot*8..+7
            bf16x8 ah[2], al[2], wh[2], wl[2];
            #pragma unroll
            for (int t = 0; t < 2; ++t) {
                const int ra = wr + t * 32 + lr;
                const int sa = slot ^ (ra & 7);
                ah[t] = *reinterpret_cast<const bf16x8*>(&sAh[ra * 64 + sa * 8]);
                al[t] = *reinterpret_cast<const bf16x8*>(&sAl[ra * 64 + sa * 8]);
                const int rw = wc + t * 32 + lr;
                const int sw = slot ^ (rw & 7);
                wh[t] = *reinterpret_cast<const bf16x8*>(&sWh[rw * 64 + sw * 8]);
                wl[t] = *reinterpret_cast<const bf16x8*>(&sWl[rw * 64 + sw * 8]);
            }
            #pragma unroll
            for (int mt = 0; mt < 2; ++mt)
                #pragma unroll
                for (int nt = 0; nt < 2; ++nt) {
                    acc[mt][nt] = __builtin_amdgcn_mfma_f32_32x32x16_bf16(
                        ah[mt], wh[nt], acc[mt][nt], 0, 0, 0);
                    acc[mt][nt] = __builtin_amdgcn_mfma_f32_32x32x16_bf16(
                        ah[mt], wl[nt], acc[mt][nt], 0, 0, 0);
                    acc[mt][nt] = __builtin_amdgcn_mfma_f32_32x32x16_bf16(
                        al[mt], wh[nt], acc[mt][nt], 0, 0, 0);
                }
        }
        __syncthreads();
    }

    // C/D: col=l&31, row=(reg&3)+8*(reg>>2)+4*(l>>5)
    #pragma unroll
    for (int mt = 0; mt < 2; ++mt)
        #pragma unroll
        for (int nt = 0; nt < 2; ++nt)
            #pragma unroll
            for (int reg = 0; reg < 16; ++reg) {
                const int row = (reg & 3) + 8 * (reg >> 2) + 4 * kg;
                C[(size_t)(bm + wr + mt * 32 + row) * N_
                  + bn + wc + nt * 32 + lr] = acc[mt][nt][reg];
            }
}

// ---------------- fp32 NT GEMM (dt GEMM) ----------------
#define BM 64
#define BN 64
#define BKT 32

template <int EPI>
__global__ __launch_bounds__(256) void gemm_nt(
    const float* __restrict__ A, int lda,
    const float* __restrict__ W, int ldw,
    float* __restrict__ C, int ldc,
    const float* __restrict__ bias,
    int M, int N, int K)
{
    __shared__ float As[BKT][BM + 4];
    __shared__ float Ws[BKT][BN + 4];

    const int tid = threadIdx.x;
    const int bm = blockIdx.y * BM;
    const int bn = blockIdx.x * BN;
    const int tx = tid & 15;
    const int ty = tid >> 4;

    float acc[4][4] = {};

    for (int k0 = 0; k0 < K; k0 += BKT) {
        #pragma unroll
        for (int i = 0; i < 2; ++i) {
            int f = tid + i * 256;
            int row = f >> 3;
            int kq  = f & 7;
            float4 v = *reinterpret_cast<const float4*>(
                &A[(size_t)(bm + row) * lda + k0 + kq * 4]);
            As[kq * 4 + 0][row] = v.x;
            As[kq * 4 + 1][row] = v.y;
            As[kq * 4 + 2][row] = v.z;
            As[kq * 4 + 3][row] = v.w;
        }
        #pragma unroll
        for (int i = 0; i < 2; ++i) {
            int f = tid + i * 256;
            int row = f >> 3;
            int kq  = f & 7;
            int gn = bn + row;
            float4 v = make_float4(0.f, 0.f, 0.f, 0.f);
            if (gn < N) {
                v = *reinterpret_cast<const float4*>(
                    &W[(size_t)gn * ldw + k0 + kq * 4]);
            }
            Ws[kq * 4 + 0][row] = v.x;
            Ws[kq * 4 + 1][row] = v.y;
            Ws[kq * 4 + 2][row] = v.z;
            Ws[kq * 4 + 3][row] = v.w;
        }
        __syncthreads();

        #pragma unroll
        for (int kk = 0; kk < BKT; ++kk) {
            float4 a4 = *reinterpret_cast<const float4*>(&As[kk][ty * 4]);
            float4 w4 = *reinterpret_cast<const float4*>(&Ws[kk][tx * 4]);
            float a[4] = {a4.x, a4.y, a4.z, a4.w};
            float wv[4] = {w4.x, w4.y, w4.z, w4.w};
            #pragma unroll
            for (int i = 0; i < 4; ++i)
                #pragma unroll
                for (int j = 0; j < 4; ++j)
                    acc[i][j] = fmaf(a[i], wv[j], acc[i][j]);
        }
        __syncthreads();
    }

    #pragma unroll
    for (int i = 0; i < 4; ++i) {
        int gm = bm + ty * 4 + i;
        #pragma unroll
        for (int j = 0; j < 4; ++j) {
            int gn = bn + tx * 4 + j;
            if (gn < N) {
                float v = acc[i][j];
                if (EPI == 1) v = softplusf(v + bias[gn]);
                C[(size_t)gm * ldc + gn] = v;
            }
        }
    }
}

// ---------------- split-K x_dbl GEMM: M=2048, N=160, K=2048 ----------------
#define XBM 64
#define XBN 32
#define XKS 8
#define XKC (D_MODEL / XKS)   // 256

__global__ __launch_bounds__(256) void xdbl_partial(
    const float* __restrict__ A,      // u (BL, D_MODEL)
    const float* __restrict__ W,      // W_xproj (160, D_MODEL)
    float* __restrict__ P)            // (XKS, BL, 160)
{
    __shared__ float As[BKT][XBM + 4];
    __shared__ float Ws[BKT][XBN + 4];

    const int tid = threadIdx.x;
    const int bm = blockIdx.y * XBM;
    const int bn = blockIdx.x * XBN;
    const int ks = blockIdx.z;
    const int tx = tid & 7;
    const int ty = tid >> 3;

    float acc[2][4] = {};

    const int kend = (ks + 1) * XKC;
    for (int k0 = ks * XKC; k0 < kend; k0 += BKT) {
        #pragma unroll
        for (int i = 0; i < 2; ++i) {
            int f = tid + i * 256;
            int row = f >> 3;
            int kq  = f & 7;
            float4 v = *reinterpret_cast<const float4*>(
                &A[(size_t)(bm + row) * D_MODEL + k0 + kq * 4]);
            As[kq * 4 + 0][row] = v.x;
            As[kq * 4 + 1][row] = v.y;
            As[kq * 4 + 2][row] = v.z;
            As[kq * 4 + 3][row] = v.w;
        }
        {
            int row = tid >> 3;
            int kq  = tid & 7;
            float4 v = *reinterpret_cast<const float4*>(
                &W[(size_t)(bn + row) * D_MODEL + k0 + kq * 4]);
            Ws[kq * 4 + 0][row] = v.x;
            Ws[kq * 4 + 1][row] = v.y;
            Ws[kq * 4 + 2][row] = v.z;
            Ws[kq * 4 + 3][row] = v.w;
        }
        __syncthreads();

        #pragma unroll
        for (int kk = 0; kk < BKT; ++kk) {
            float a0 = As[kk][ty * 2 + 0];
            float a1 = As[kk][ty * 2 + 1];
            float4 w4 = *reinterpret_cast<const float4*>(&Ws[kk][tx * 4]);
            float wv[4] = {w4.x, w4.y, w4.z, w4.w};
            #pragma unroll
            for (int j = 0; j < 4; ++j) {
                acc[0][j] = fmaf(a0, wv[j], acc[0][j]);
                acc[1][j] = fmaf(a1, wv[j], acc[1][j]);
            }
        }
        __syncthreads();
    }

    #pragma unroll
    for (int i = 0; i < 2; ++i) {
        const int gm = bm + ty * 2 + i;
        #pragma unroll
        for (int j = 0; j < 4; ++j) {
            const int gn = bn + tx * 4 + j;
            P[((size_t)ks * BL + gm) * XPROJ_N + gn] = acc[i][j];
        }
    }
}

__global__ __launch_bounds__(256) void xdbl_reduce(
    const float* __restrict__ P, float* __restrict__ xdbl)
{
    const int i = blockIdx.x * 256 + threadIdx.x;
    const int n4 = BL * XPROJ_N / 4;
    if (i >= n4) return;
    float4 s = *reinterpret_cast<const float4*>(&P[(size_t)i * 4]);
    #pragma unroll
    for (int ks = 1; ks < XKS; ++ks) {
        float4 v = *reinterpret_cast<const float4*>(
            &P[(size_t)ks * BL * XPROJ_N + (size_t)i * 4]);
        s.x += v.x; s.y += v.y; s.z += v.z; s.w += v.w;
    }
    *reinterpret_cast<float4*>(&xdbl[(size_t)i * 4]) = s;
}

// ------------- depthwise causal conv (K=4) + SiLU, 4 channels/thread -------------
__global__ __launch_bounds__(256) void conv_silu_kernel(
    const float* __restrict__ xz,      // (BL, 4096); u_raw = cols [0, 2048)
    const float* __restrict__ conv_w,  // (D, 4)
    const float* __restrict__ conv_b,  // (D,)
    float* __restrict__ u)             // (BL, D)
{
    int idx = blockIdx.x * 256 + threadIdx.x;      // over BL * D/4
    if (idx >= BL * (D_MODEL / 4)) return;
    const int d4 = (idx & (D_MODEL / 4 - 1)) * 4;
    const int bl = idx >> 9;                        // / (D/4)
    const int l  = bl & (SEQ - 1);
    const int b  = bl >> 10;

    float4 cb = *reinterpret_cast<const float4*>(&conv_b[d4]);
    float4 cw[4];
    #pragma unroll
    for (int j = 0; j < 4; ++j)
        cw[j] = *reinterpret_cast<const float4*>(&conv_w[(d4 + j) * KER]);

    float acc[4] = {cb.x, cb.y, cb.z, cb.w};
    #pragma unroll
    for (int k = 0; k < KER; ++k) {
        const int ls = l - (KER - 1) + k;
        if (ls >= 0) {
            float4 v = *reinterpret_cast<const float4*>(
                &xz[(size_t)(b * SEQ + ls) * (2 * D_MODEL) + d4]);
            acc[0] = fmaf((&cw[0].x)[k], v.x, acc[0]);
            acc[1] = fmaf((&cw[1].x)[k], v.y, acc[1]);
            acc[2] = fmaf((&cw[2].x)[k], v.z, acc[2]);
            acc[3] = fmaf((&cw[3].x)[k], v.w, acc[3]);
        }
    }
    float4 o;
    o.x = siluf(acc[0]); o.y = siluf(acc[1]);
    o.z = siluf(acc[2]); o.w = siluf(acc[3]);
    *reinterpret_cast<float4*>(&u[(size_t)bl * D_MODEL + d4]) = o;
}

// ---------------- chunked selective scan ----------------
__global__ __launch_bounds__(256) void scan_part1(
    const float* __restrict__ dt,
    const float* __restrict__ xdbl,
    const float* __restrict__ u,
    const float* __restrict__ A_log,
    float* __restrict__ PH,
    float* __restrict__ Hend)
{
    const int tid = threadIdx.x;
    const int d   = blockIdx.x * 256 + tid;
    const int bc  = blockIdx.y;
    const int b   = bc >> 5;
    const int c   = bc & (NC - 1);

    float A[16];
    #pragma unroll
    for (int q = 0; q < 4; ++q) {
        float4 v = *reinterpret_cast<const float4*>(&A_log[d * 16 + q * 4]);
        A[q*4+0] = -__expf(v.x); A[q*4+1] = -__expf(v.y);
        A[q*4+2] = -__expf(v.z); A[q*4+3] = -__expf(v.w);
    }
    float h[16] = {};
    float P[16];
    #pragma unroll
    for (int n = 0; n < 16; ++n) P[n] = 1.f;

    const size_t row0 = (size_t)b * SEQ + c * TC;
    for (int t = 0; t < TC; ++t) {
        const size_t row = row0 + t;
        const float dtv = dt[row * D_MODEL + d];
        const float uv  = u[row * D_MODEL + d];
        float Bv[16];
        const float4* Bp = reinterpret_cast<const float4*>(&xdbl[row * XPROJ_N + DT_RANK]);
        #pragma unroll
        for (int q = 0; q < 4; ++q) {
            float4 v = Bp[q];
            Bv[q*4+0] = v.x; Bv[q*4+1] = v.y; Bv[q*4+2] = v.z; Bv[q*4+3] = v.w;
        }
        const float dtu = dtv * uv;
        #pragma unroll
        for (int n = 0; n < 16; ++n) {
            float dA = __expf(dtv * A[n]);
            h[n] = fmaf(dA, h[n], dtu * Bv[n]);
            P[n] *= dA;
        }
    }
    const size_t off = ((size_t)bc * D_MODEL + d) * 16;
    #pragma unroll
    for (int q = 0; q < 4; ++q) {
        *reinterpret_cast<float4*>(&PH[off + q*4])   =
            make_float4(P[q*4+0], P[q*4+1], P[q*4+2], P[q*4+3]);
        *reinterpret_cast<float4*>(&Hend[off + q*4]) =
            make_float4(h[q*4+0], h[q*4+1], h[q*4+2], h[q*4+3]);
    }
}

__global__ __launch_bounds__(256) void scan_part2(
    float* __restrict__ PH,
    const float* __restrict__ Hend)
{
    const int g  = blockIdx.x * 256 + threadIdx.x;
    const int b  = g >> 15;
    const int dn = g & 32767;
    float h = 0.f;
    #pragma unroll
    for (int c = 0; c < NC; ++c) {
        const size_t off = ((size_t)(b * NC + c) * D_MODEL * 16) + dn;
        const float p  = PH[off];
        const float he = Hend[off];
        PH[off] = h;
        h = fmaf(p, h, he);
    }
}

// S3: replay each chunk from its true Hstart; emit gated output directly as
// bf16 hi/lo planes (fused split — feeds GEMM6, saves one pass + dispatch).
__global__ __launch_bounds__(256) void scan_part3(
    const float* __restrict__ dt,
    const float* __restrict__ xdbl,
    const float* __restrict__ xz,
    const float* __restrict__ u,
    const float* __restrict__ A_log,
    const float* __restrict__ Dskip,
    const float* __restrict__ PH,
    __bf16* __restrict__ yh, __bf16* __restrict__ yl)
{
    const int tid = threadIdx.x;
    const int d   = blockIdx.x * 256 + tid;
    const int bc  = blockIdx.y;
    const int b   = bc >> 5;
    const int c   = bc & (NC - 1);

    float A[16];
    #pragma unroll
    for (int q = 0; q < 4; ++q) {
        float4 v = *reinterpret_cast<const float4*>(&A_log[d * 16 + q * 4]);
        A[q*4+0] = -__expf(v.x); A[q*4+1] = -__expf(v.y);
        A[q*4+2] = -__expf(v.z); A[q*4+3] = -__expf(v.w);
    }
    float h[16];
    const size_t off = ((size_t)bc * D_MODEL + d) * 16;
    #pragma unroll
    for (int q = 0; q < 4; ++q) {
        float4 v = *reinterpret_cast<const float4*>(&PH[off + q*4]);
        h[q*4+0] = v.x; h[q*4+1] = v.y; h[q*4+2] = v.z; h[q*4+3] = v.w;
    }
    const float Dk = Dskip[d];

    const size_t row0 = (size_t)b * SEQ + c * TC;
    for (int t = 0; t < TC; ++t) {
        const size_t row = row0 + t;
        const float dtv = dt[row * D_MODEL + d];
        const float uv  = u[row * D_MODEL + d];
        float Bv[16], Cv[16];
        const float4* Bp = reinterpret_cast<const float4*>(&xdbl[row * XPROJ_N + DT_RANK]);
        const float4* Cp = reinterpret_cast<const float4*>(&xdbl[row * XPROJ_N + DT_RANK + D_STATE]);
        #pragma unroll
        for (int q = 0; q < 4; ++q) {
            float4 v = Bp[q];
            Bv[q*4+0] = v.x; Bv[q*4+1] = v.y; Bv[q*4+2] = v.z; Bv[q*4+3] = v.w;
            float4 wv = Cp[q];
            Cv[q*4+0] = wv.x; Cv[q*4+1] = wv.y; Cv[q*4+2] = wv.z; Cv[q*4+3] = wv.w;
        }
        const float dtu = dtv * uv;
        float y = 0.f;
        #pragma unroll
        for (int n = 0; n < 16; ++n) {
            float dA = __expf(dtv * A[n]);
            h[n] = fmaf(dA, h[n], dtu * Bv[n]);
            y = fmaf(h[n], Cv[n], y);
        }
        const float zv = xz[row * (2 * D_MODEL) + D_MODEL + d];
        const float yv = (y + uv * Dk) * siluf(zv);
        const __bf16 hv = (__bf16)yv;
        yh[row * D_MODEL + d] = hv;
        yl[row * D_MODEL + d] = (__bf16)(yv - (float)hv);
    }
}

// ---------------- launch ----------------
extern "C" void kernel_launch(void* const* d_in, const int* in_sizes, int n_in,
                              void* d_out, int out_size, void* d_ws, size_t ws_size,
                              hipStream_t stream) {
    const float* x       = (const float*)d_in[0];
    const float* W_in    = (const float*)d_in[1];
    const float* conv_w  = (const float*)d_in[2];
    const float* conv_b  = (const float*)d_in[3];
    const float* W_xproj = (const float*)d_in[4];
    const float* W_dt    = (const float*)d_in[5];
    const float* b_dt    = (const float*)d_in[6];
    const float* A_log   = (const float*)d_in[7];
    const float* Dskip   = (const float*)d_in[8];
    const float* W_out   = (const float*)d_in[9];
    float* out = (float*)d_out;

    float* ws = (float*)d_ws;
    const size_t M1 = 1024 * 1024;
    float* xz   = ws;                        // 8M fp32
    float* u    = ws + 8 * M1;               // 4M
    float* xdbl = ws + 12 * M1;              // 0.5M
    float* dt   = ws + 12 * M1 + 512 * 1024; // 4M
    float* PH   = dt + 4 * M1;               // 2M
    float* Hend = PH + 2 * M1;               // 2M

    __bf16* planes = (__bf16*)(ws + 25 * M1);
    __bf16* xh  = planes;                    // 4M bf16
    __bf16* xl  = xh + 4 * M1;               // 4M
    __bf16* wih = xl + 4 * M1;               // 8M
    __bf16* wil = wih + 8 * M1;              // 8M
    // reuse regions (stream-ordered; producers run after prior consumers):
    __bf16* woh = wih;                       // W_in planes dead after GEMM1
    __bf16* wol = wih + 4 * M1;
    __bf16* yh  = xh;                        // x planes dead after GEMM1
    __bf16* yl  = xl;
    float* xpart = (float*)(ws + 25 * M1);   // dead x-plane region; consumed by
                                             // xdbl_reduce before scan_part3
                                             // writes yh/yl over it.

    // split x and W_in to bf16 hi/lo planes (one merged dispatch)
    split_xwi_kernel<<<2048, 256, 0, stream>>>(x, xh, xl, W_in, wih, wil);

    // 1) xz = x @ W_in.T  (MFMA split-bf16, 32x32x16, XCD-swizzled)
    {
        dim3 grid(2 * D_MODEL / 128, BL / 128);
        gemm_bf3<<<grid, 256, 0, stream>>>(xh, xl, wih, wil, xz, 2 * D_MODEL, D_MODEL);
    }
    // 2) conv + silu (vectorized x4)
    conv_silu_kernel<<<BL * (D_MODEL / 4) / 256, 256, 0, stream>>>(xz, conv_w, conv_b, u);

    // split W_out (reuses W_in plane region; GEMM1 already consumed it)
    split_kernel<<<(D_MODEL * D_MODEL / 4 + 255) / 256, 256, 0, stream>>>(
        W_out, woh, wol, D_MODEL * D_MODEL / 4);

    // 3) x_dbl = u @ W_xproj.T  (fp32 split-K; xpart overwrites dead x planes)
    {
        dim3 grid(XPROJ_N / XBN, BL / XBM, XKS);
        xdbl_partial<<<grid, 256, 0, stream>>>(u, W_xproj, xpart);
        xdbl_reduce<<<(BL * XPROJ_N / 4 + 255) / 256, 256, 0, stream>>>(xpart, xdbl);
    }
    // 4) dt = softplus(x_dbl[:, :128] @ W_dt.T + b_dt)  (fp32)
    {
        dim3 grid(D_MODEL / BN, BL / BM);
        gemm_nt<1><<<grid, 256, 0, stream>>>(xdbl, XPROJ_N, W_dt, DT_RANK,
                                             dt, D_MODEL, b_dt,
                                             BL, D_MODEL, DT_RANK);
    }
    // 5) chunked scan; S3 emits yh/yl bf16 planes directly (fused split)
    {
        dim3 grid(D_MODEL / 256, B_SZ * NC);
        scan_part1<<<grid, 256, 0, stream>>>(dt, xdbl, u, A_log, PH, Hend);
        scan_part2<<<B_SZ * D_MODEL * 16 / 256, 256, 0, stream>>>(PH, Hend);
        scan_part3<<<grid, 256, 0, stream>>>(dt, xdbl, xz, u, A_log, Dskip, PH, yh, yl);
    }
    // 6) out = yact @ W_out.T  (MFMA split-bf16, 32x32x16, XCD-swizzled)
    {
        dim3 grid(D_MODEL / 128, BL / 128);
        gemm_bf3<<<grid, 256, 0, stream>>>(yh, yl, woh, wol, out, D_MODEL, D_MODEL);
    }
}

// Round 10
// 398.225 us; speedup vs baseline: 1.0651x; 1.0651x over previous
//
#include <hip/hip_runtime.h>
#include <hip/hip_bf16.h>

// Mamba block — split-bf16 MFMA GEMMs (proven 16x16 schedule) + chunked scan.
//  0) split x,W_in,W_out,W_dt -> bf16 hi/lo planes (ONE dispatch)
//  1) xz = x @ W_in.T      (2048x4096, K=2048)  MFMA split-bf16  -> ws.xz (fp32)
//  2) u  = silu(conv4(xz[:, :2048]))            vectorized x4    -> ws.u
//  3) x_dbl = u @ W_xproj.T (2048x160, K=2048)  fp32 split-K(8); reduce also
//     emits bf16 planes of x_dbl[:, :128]                        -> ws.xdbl,xdh/xdl
//  4) dt = softplus(dt_r @ W_dt.T + b_dt)       MFMA split-bf16  -> ws.dt
//  5) chunked scan (S1/S2/S3), S3 emits yh/yl bf16 planes fused  -> ws.yh/yl
//  6) out = yact @ W_out.T (2048x2048, K=2048)  MFMA split-bf16  -> d_out
//
// HISTORY (measured):
//  r6: BK=32 dbuf prefetch w/ per-step __syncthreads: REGRESSED (57->47 MfmaUtil).
//  r8: 32x32x16 MFMA: uniform 4/ds_read bank conflict (8.39M/dispatch);
//      XCD swizzle: FETCH 82->139MB. Both reverted.
//  16x16x32 + both-sides XOR swizzle slot^=(row&7) is the local opt:
//  83.5us, MfmaUtil 57%, 0 conflicts, ~1230 TF effective MFMA rate.

#define D_MODEL 2048
#define D_STATE 16
#define KER 4
#define DT_RANK 128
#define B_SZ 2
#define SEQ 1024
#define BL (B_SZ * SEQ)
#define XPROJ_N (DT_RANK + 2 * D_STATE)  // 160
#define NC 32
#define TC (SEQ / NC)

using f32x4  = __attribute__((ext_vector_type(4))) float;
using bf16x8 = __attribute__((ext_vector_type(8))) __bf16;
using bf16x4 = __attribute__((ext_vector_type(4))) __bf16;

__device__ __forceinline__ float softplusf(float x) {
    return (x > 20.f) ? x : log1pf(__expf(x));
}
__device__ __forceinline__ float siluf(float x) {
    return x / (1.f + __expf(-x));
}

// ---------------- fp32 -> (hi, lo) bf16 plane split ----------------
__device__ __forceinline__ void split4(const float* __restrict__ src,
                                       __bf16* __restrict__ hi,
                                       __bf16* __restrict__ lo, int i) {
    float4 v = *reinterpret_cast<const float4*>(&src[(size_t)i * 4]);
    bf16x4 hv, lv;
    float f[4] = {v.x, v.y, v.z, v.w};
    #pragma unroll
    for (int j = 0; j < 4; ++j) {
        __bf16 h = (__bf16)f[j];
        hv[j] = h;
        lv[j] = (__bf16)(f[j] - (float)h);
    }
    *reinterpret_cast<bf16x4*>(&hi[(size_t)i * 4]) = hv;
    *reinterpret_cast<bf16x4*>(&lo[(size_t)i * 4]) = lv;
}

// merged x + W_in + W_out + W_dt split (one dispatch), grid-stride.
// W_out/W_dt planes live in dedicated workspace (no aliasing), so all
// input prep happens before GEMM1.
__global__ __launch_bounds__(256) void split_all_kernel(
    const float* __restrict__ x,  __bf16* __restrict__ xh,  __bf16* __restrict__ xl,
    const float* __restrict__ wi, __bf16* __restrict__ wih, __bf16* __restrict__ wil,
    const float* __restrict__ wo, __bf16* __restrict__ woh, __bf16* __restrict__ wol,
    const float* __restrict__ wd, __bf16* __restrict__ wdh, __bf16* __restrict__ wdl)
{
    const int NX = BL * D_MODEL / 4;            // 1,048,576 float4s
    const int NI = 2 * D_MODEL * D_MODEL / 4;   // 2,097,152
    const int NO = D_MODEL * D_MODEL / 4;       // 1,048,576
    const int ND = D_MODEL * DT_RANK / 4;       // 65,536
    const int total = NX + NI + NO + ND;
    for (int i = blockIdx.x * 256 + threadIdx.x; i < total; i += gridDim.x * 256) {
        if      (i < NX)           split4(x,  xh,  xl,  i);
        else if (i < NX + NI)      split4(wi, wih, wil, i - NX);
        else if (i < NX + NI + NO) split4(wo, woh, wol, i - NX - NI);
        else                       split4(wd, wdh, wdl, i - NX - NI - NO);
    }
}

// ---------------- split-bf16 MFMA NT GEMM (16x16x32, proven) ----------------
// C[m][n] = sum_k A[m,k]*W[n,k], A ~ Ah+Al, W ~ Wh+Wl (drop Al*Wl).
// 128x128 tile, BK=64, 4 waves (2x2 of 64x64), mfma_f32_16x16x32_bf16.
// LDS linear row-major [128][64] bf16 per plane; XOR swizzle slot^=(row&7)
// applied on BOTH global source (pre-swizzle) and ds_read (rule #21).
// EPI: 0 = store raw, 1 = softplus(acc + bias[col]).
template <int EPI>
__global__ __launch_bounds__(256, 2) void gemm_bf3(
    const __bf16* __restrict__ Ah, const __bf16* __restrict__ Al,
    const __bf16* __restrict__ Wh, const __bf16* __restrict__ Wl,
    float* __restrict__ C, const float* __restrict__ bias, int N_, int K)
{
    __shared__ __align__(16) __bf16 lds[4 * 128 * 64];
    __bf16* sAh = lds;
    __bf16* sAl = lds + 8192;
    __bf16* sWh = lds + 16384;
    __bf16* sWl = lds + 24576;

    const int tid = threadIdx.x;
    const int bm = blockIdx.y * 128;
    const int bn = blockIdx.x * 128;
    const int w  = tid >> 6;
    const int l  = tid & 63;
    const int wr = (w >> 1) * 64;
    const int wc = (w & 1) * 64;
    const int fr = l & 15;
    const int fq = l >> 4;

    f32x4 acc[4][4] = {};

    for (int k0 = 0; k0 < K; k0 += 64) {
        #pragma unroll
        for (int i = 0; i < 4; ++i) {
            const int f  = i * 256 + tid;   // 16B chunk id 0..1023
            const int r  = f >> 3;          // tile row 0..127
            const int ss = f & 7;           // dest slot
            const int gs = ss ^ (r & 7);    // pre-swizzled source slot
            const size_t ga = (size_t)(bm + r) * K + k0 + gs * 8;
            const size_t gw = (size_t)(bn + r) * K + k0 + gs * 8;
            __builtin_amdgcn_global_load_lds(
                (const __attribute__((address_space(1))) void*)(Ah + ga),
                (__attribute__((address_space(3))) void*)(sAh + (size_t)f * 8), 16, 0, 0);
            __builtin_amdgcn_global_load_lds(
                (const __attribute__((address_space(1))) void*)(Al + ga),
                (__attribute__((address_space(3))) void*)(sAl + (size_t)f * 8), 16, 0, 0);
            __builtin_amdgcn_global_load_lds(
                (const __attribute__((address_space(1))) void*)(Wh + gw),
                (__attribute__((address_space(3))) void*)(sWh + (size_t)f * 8), 16, 0, 0);
            __builtin_amdgcn_global_load_lds(
                (const __attribute__((address_space(1))) void*)(Wl + gw),
                (__attribute__((address_space(3))) void*)(sWl + (size_t)f * 8), 16, 0, 0);
        }
        __syncthreads();

        #pragma unroll
        for (int ks = 0; ks < 2; ++ks) {
            bf16x8 ah[4], al[4], wh[4], wl[4];
            #pragma unroll
            for (int t = 0; t < 4; ++t) {
                const int ra = wr + t * 16 + fr;
                const int sa = (ks * 4 + fq) ^ (ra & 7);
                ah[t] = *reinterpret_cast<const bf16x8*>(&sAh[ra * 64 + sa * 8]);
                al[t] = *reinterpret_cast<const bf16x8*>(&sAl[ra * 64 + sa * 8]);
                const int rw = wc + t * 16 + fr;
                const int sw = (ks * 4 + fq) ^ (rw & 7);
                wh[t] = *reinterpret_cast<const bf16x8*>(&sWh[rw * 64 + sw * 8]);
                wl[t] = *reinterpret_cast<const bf16x8*>(&sWl[rw * 64 + sw * 8]);
            }
            #pragma unroll
            for (int mt = 0; mt < 4; ++mt)
                #pragma unroll
                for (int nt = 0; nt < 4; ++nt) {
                    acc[mt][nt] = __builtin_amdgcn_mfma_f32_16x16x32_bf16(
                        ah[mt], wh[nt], acc[mt][nt], 0, 0, 0);
                    acc[mt][nt] = __builtin_amdgcn_mfma_f32_16x16x32_bf16(
                        ah[mt], wl[nt], acc[mt][nt], 0, 0, 0);
                    acc[mt][nt] = __builtin_amdgcn_mfma_f32_16x16x32_bf16(
                        al[mt], wh[nt], acc[mt][nt], 0, 0, 0);
                }
        }
        __syncthreads();
    }

    // C/D layout (m89-verified): col = lane&15, row = (lane>>4)*4 + reg
    #pragma unroll
    for (int mt = 0; mt < 4; ++mt)
        #pragma unroll
        for (int nt = 0; nt < 4; ++nt) {
            const int gn = bn + wc + nt * 16 + fr;
            #pragma unroll
            for (int j = 0; j < 4; ++j) {
                float v = acc[mt][nt][j];
                if (EPI == 1) v = softplusf(v + bias[gn]);
                C[(size_t)(bm + wr + mt * 16 + fq * 4 + j) * N_ + gn] = v;
            }
        }
}

// ---------------- split-K x_dbl GEMM: M=2048, N=160, K=2048 ----------------
#define BKT 32
#define XBM 64
#define XBN 32
#define XKS 8
#define XKC (D_MODEL / XKS)   // 256

__global__ __launch_bounds__(256) void xdbl_partial(
    const float* __restrict__ A,      // u (BL, D_MODEL)
    const float* __restrict__ W,      // W_xproj (160, D_MODEL)
    float* __restrict__ P)            // (XKS, BL, 160)
{
    __shared__ float As[BKT][XBM + 4];
    __shared__ float Ws[BKT][XBN + 4];

    const int tid = threadIdx.x;
    const int bm = blockIdx.y * XBM;
    const int bn = blockIdx.x * XBN;
    const int ks = blockIdx.z;
    const int tx = tid & 7;
    const int ty = tid >> 3;

    float acc[2][4] = {};

    const int kend = (ks + 1) * XKC;
    for (int k0 = ks * XKC; k0 < kend; k0 += BKT) {
        #pragma unroll
        for (int i = 0; i < 2; ++i) {
            int f = tid + i * 256;
            int row = f >> 3;
            int kq  = f & 7;
            float4 v = *reinterpret_cast<const float4*>(
                &A[(size_t)(bm + row) * D_MODEL + k0 + kq * 4]);
            As[kq * 4 + 0][row] = v.x;
            As[kq * 4 + 1][row] = v.y;
            As[kq * 4 + 2][row] = v.z;
            As[kq * 4 + 3][row] = v.w;
        }
        {
            int row = tid >> 3;
            int kq  = tid & 7;
            float4 v = *reinterpret_cast<const float4*>(
                &W[(size_t)(bn + row) * D_MODEL + k0 + kq * 4]);
            Ws[kq * 4 + 0][row] = v.x;
            Ws[kq * 4 + 1][row] = v.y;
            Ws[kq * 4 + 2][row] = v.z;
            Ws[kq * 4 + 3][row] = v.w;
        }
        __syncthreads();

        #pragma unroll
        for (int kk = 0; kk < BKT; ++kk) {
            float a0 = As[kk][ty * 2 + 0];
            float a1 = As[kk][ty * 2 + 1];
            float4 w4 = *reinterpret_cast<const float4*>(&Ws[kk][tx * 4]);
            float wv[4] = {w4.x, w4.y, w4.z, w4.w};
            #pragma unroll
            for (int j = 0; j < 4; ++j) {
                acc[0][j] = fmaf(a0, wv[j], acc[0][j]);
                acc[1][j] = fmaf(a1, wv[j], acc[1][j]);
            }
        }
        __syncthreads();
    }

    #pragma unroll
    for (int i = 0; i < 2; ++i) {
        const int gm = bm + ty * 2 + i;
        #pragma unroll
        for (int j = 0; j < 4; ++j) {
            const int gn = bn + tx * 4 + j;
            P[((size_t)ks * BL + gm) * XPROJ_N + gn] = acc[i][j];
        }
    }
}

// reduce 8 partials -> xdbl; additionally emit bf16 hi/lo planes of the
// dt_r slice (cols < 128) feeding the MFMA dt-GEMM.
__global__ __launch_bounds__(256) void xdbl_reduce(
    const float* __restrict__ P, float* __restrict__ xdbl,
    __bf16* __restrict__ xdh, __bf16* __restrict__ xdl)
{
    const int i = blockIdx.x * 256 + threadIdx.x;
    const int n4 = BL * XPROJ_N / 4;
    if (i >= n4) return;
    float4 s = *reinterpret_cast<const float4*>(&P[(size_t)i * 4]);
    #pragma unroll
    for (int ks = 1; ks < XKS; ++ks) {
        float4 v = *reinterpret_cast<const float4*>(
            &P[(size_t)ks * BL * XPROJ_N + (size_t)i * 4]);
        s.x += v.x; s.y += v.y; s.z += v.z; s.w += v.w;
    }
    *reinterpret_cast<float4*>(&xdbl[(size_t)i * 4]) = s;

    const int row = i / (XPROJ_N / 4);          // = i / 40
    const int col = (i % (XPROJ_N / 4)) * 4;
    if (col < DT_RANK) {
        bf16x4 hv, lv;
        float f[4] = {s.x, s.y, s.z, s.w};
        #pragma unroll
        for (int j = 0; j < 4; ++j) {
            __bf16 h = (__bf16)f[j];
            hv[j] = h;
            lv[j] = (__bf16)(f[j] - (float)h);
        }
        *reinterpret_cast<bf16x4*>(&xdh[(size_t)row * DT_RANK + col]) = hv;
        *reinterpret_cast<bf16x4*>(&xdl[(size_t)row * DT_RANK + col]) = lv;
    }
}

// ------------- depthwise causal conv (K=4) + SiLU, 4 channels/thread -------------
__global__ __launch_bounds__(256) void conv_silu_kernel(
    const float* __restrict__ xz,      // (BL, 4096); u_raw = cols [0, 2048)
    const float* __restrict__ conv_w,  // (D, 4)
    const float* __restrict__ conv_b,  // (D,)
    float* __restrict__ u)             // (BL, D)
{
    int idx = blockIdx.x * 256 + threadIdx.x;      // over BL * D/4
    if (idx >= BL * (D_MODEL / 4)) return;
    const int d4 = (idx & (D_MODEL / 4 - 1)) * 4;
    const int bl = idx >> 9;                        // / (D/4)
    const int l  = bl & (SEQ - 1);
    const int b  = bl >> 10;

    float4 cb = *reinterpret_cast<const float4*>(&conv_b[d4]);
    float4 cw[4];
    #pragma unroll
    for (int j = 0; j < 4; ++j)
        cw[j] = *reinterpret_cast<const float4*>(&conv_w[(d4 + j) * KER]);

    float acc[4] = {cb.x, cb.y, cb.z, cb.w};
    #pragma unroll
    for (int k = 0; k < KER; ++k) {
        const int ls = l - (KER - 1) + k;
        if (ls >= 0) {
            float4 v = *reinterpret_cast<const float4*>(
                &xz[(size_t)(b * SEQ + ls) * (2 * D_MODEL) + d4]);
            acc[0] = fmaf((&cw[0].x)[k], v.x, acc[0]);
            acc[1] = fmaf((&cw[1].x)[k], v.y, acc[1]);
            acc[2] = fmaf((&cw[2].x)[k], v.z, acc[2]);
            acc[3] = fmaf((&cw[3].x)[k], v.w, acc[3]);
        }
    }
    float4 o;
    o.x = siluf(acc[0]); o.y = siluf(acc[1]);
    o.z = siluf(acc[2]); o.w = siluf(acc[3]);
    *reinterpret_cast<float4*>(&u[(size_t)bl * D_MODEL + d4]) = o;
}

// ---------------- chunked selective scan ----------------
__global__ __launch_bounds__(256) void scan_part1(
    const float* __restrict__ dt,
    const float* __restrict__ xdbl,
    const float* __restrict__ u,
    const float* __restrict__ A_log,
    float* __restrict__ PH,
    float* __restrict__ Hend)
{
    const int tid = threadIdx.x;
    const int d   = blockIdx.x * 256 + tid;
    const int bc  = blockIdx.y;
    const int b   = bc >> 5;
    const int c   = bc & (NC - 1);

    float A[16];
    #pragma unroll
    for (int q = 0; q < 4; ++q) {
        float4 v = *reinterpret_cast<const float4*>(&A_log[d * 16 + q * 4]);
        A[q*4+0] = -__expf(v.x); A[q*4+1] = -__expf(v.y);
        A[q*4+2] = -__expf(v.z); A[q*4+3] = -__expf(v.w);
    }
    float h[16] = {};
    float P[16];
    #pragma unroll
    for (int n = 0; n < 16; ++n) P[n] = 1.f;

    const size_t row0 = (size_t)b * SEQ + c * TC;
    for (int t = 0; t < TC; ++t) {
        const size_t row = row0 + t;
        const float dtv = dt[row * D_MODEL + d];
        const float uv  = u[row * D_MODEL + d];
        float Bv[16];
        const float4* Bp = reinterpret_cast<const float4*>(&xdbl[row * XPROJ_N + DT_RANK]);
        #pragma unroll
        for (int q = 0; q < 4; ++q) {
            float4 v = Bp[q];
            Bv[q*4+0] = v.x; Bv[q*4+1] = v.y; Bv[q*4+2] = v.z; Bv[q*4+3] = v.w;
        }
        const float dtu = dtv * uv;
        #pragma unroll
        for (int n = 0; n < 16; ++n) {
            float dA = __expf(dtv * A[n]);
            h[n] = fmaf(dA, h[n], dtu * Bv[n]);
            P[n] *= dA;
        }
    }
    const size_t off = ((size_t)bc * D_MODEL + d) * 16;
    #pragma unroll
    for (int q = 0; q < 4; ++q) {
        *reinterpret_cast<float4*>(&PH[off + q*4])   =
            make_float4(P[q*4+0], P[q*4+1], P[q*4+2], P[q*4+3]);
        *reinterpret_cast<float4*>(&Hend[off + q*4]) =
            make_float4(h[q*4+0], h[q*4+1], h[q*4+2], h[q*4+3]);
    }
}

__global__ __launch_bounds__(256) void scan_part2(
    float* __restrict__ PH,
    const float* __restrict__ Hend)
{
    const int g  = blockIdx.x * 256 + threadIdx.x;
    const int b  = g >> 15;
    const int dn = g & 32767;
    float h = 0.f;
    #pragma unroll
    for (int c = 0; c < NC; ++c) {
        const size_t off = ((size_t)(b * NC + c) * D_MODEL * 16) + dn;
        const float p  = PH[off];
        const float he = Hend[off];
        PH[off] = h;
        h = fmaf(p, h, he);
    }
}

// S3: replay each chunk from its true Hstart; emit gated output directly as
// bf16 hi/lo planes (fused split — feeds GEMM6, saves one pass + dispatch).
__global__ __launch_bounds__(256) void scan_part3(
    const float* __restrict__ dt,
    const float* __restrict__ xdbl,
    const float* __restrict__ xz,
    const float* __restrict__ u,
    const float* __restrict__ A_log,
    const float* __restrict__ Dskip,
    const float* __restrict__ PH,
    __bf16* __restrict__ yh, __bf16* __restrict__ yl)
{
    const int tid = threadIdx.x;
    const int d   = blockIdx.x * 256 + tid;
    const int bc  = blockIdx.y;
    const int b   = bc >> 5;
    const int c   = bc & (NC - 1);

    float A[16];
    #pragma unroll
    for (int q = 0; q < 4; ++q) {
        float4 v = *reinterpret_cast<const float4*>(&A_log[d * 16 + q * 4]);
        A[q*4+0] = -__expf(v.x); A[q*4+1] = -__expf(v.y);
        A[q*4+2] = -__expf(v.z); A[q*4+3] = -__expf(v.w);
    }
    float h[16];
    const size_t off = ((size_t)bc * D_MODEL + d) * 16;
    #pragma unroll
    for (int q = 0; q < 4; ++q) {
        float4 v = *reinterpret_cast<const float4*>(&PH[off + q*4]);
        h[q*4+0] = v.x; h[q*4+1] = v.y; h[q*4+2] = v.z; h[q*4+3] = v.w;
    }
    const float Dk = Dskip[d];

    const size_t row0 = (size_t)b * SEQ + c * TC;
    for (int t = 0; t < TC; ++t) {
        const size_t row = row0 + t;
        const float dtv = dt[row * D_MODEL + d];
        const float uv  = u[row * D_MODEL + d];
        float Bv[16], Cv[16];
        const float4* Bp = reinterpret_cast<const float4*>(&xdbl[row * XPROJ_N + DT_RANK]);
        const float4* Cp = reinterpret_cast<const float4*>(&xdbl[row * XPROJ_N + DT_RANK + D_STATE]);
        #pragma unroll
        for (int q = 0; q < 4; ++q) {
            float4 v = Bp[q];
            Bv[q*4+0] = v.x; Bv[q*4+1] = v.y; Bv[q*4+2] = v.z; Bv[q*4+3] = v.w;
            float4 wv = Cp[q];
            Cv[q*4+0] = wv.x; Cv[q*4+1] = wv.y; Cv[q*4+2] = wv.z; Cv[q*4+3] = wv.w;
        }
        const float dtu = dtv * uv;
        float y = 0.f;
        #pragma unroll
        for (int n = 0; n < 16; ++n) {
            float dA = __expf(dtv * A[n]);
            h[n] = fmaf(dA, h[n], dtu * Bv[n]);
            y = fmaf(h[n], Cv[n], y);
        }
        const float zv = xz[row * (2 * D_MODEL) + D_MODEL + d];
        const float yv = (y + uv * Dk) * siluf(zv);
        const __bf16 hv = (__bf16)yv;
        yh[row * D_MODEL + d] = hv;
        yl[row * D_MODEL + d] = (__bf16)(yv - (float)hv);
    }
}

// ---------------- launch ----------------
extern "C" void kernel_launch(void* const* d_in, const int* in_sizes, int n_in,
                              void* d_out, int out_size, void* d_ws, size_t ws_size,
                              hipStream_t stream) {
    const float* x       = (const float*)d_in[0];
    const float* W_in    = (const float*)d_in[1];
    const float* conv_w  = (const float*)d_in[2];
    const float* conv_b  = (const float*)d_in[3];
    const float* W_xproj = (const float*)d_in[4];
    const float* W_dt    = (const float*)d_in[5];
    const float* b_dt    = (const float*)d_in[6];
    const float* A_log   = (const float*)d_in[7];
    const float* Dskip   = (const float*)d_in[8];
    const float* W_out   = (const float*)d_in[9];
    float* out = (float*)d_out;

    float* ws = (float*)d_ws;
    const size_t M1 = 1024 * 1024;
    // fp32 region [0, 20.5M floats)
    float* xz   = ws;                        // 8M fp32
    float* u    = ws + 8 * M1;               // 4M
    float* xdbl = ws + 12 * M1;              // 0.5M reserved
    float* dt   = ws + 12 * M1 + 512 * 1024; // 4M
    float* PH   = dt + 4 * M1;               // 2M
    float* Hend = PH + 2 * M1;               // 2M   (ends at 20.5M floats)
    // dedicated plane region [20.5M, 25M floats) = 18 MB, exactly:
    __bf16* woh = (__bf16*)(ws + 20 * M1 + 512 * 1024);  // 4M bf16
    __bf16* wol = woh + 4 * M1;                          // 4M
    __bf16* wdh = wol + 4 * M1;                          // 0.25M
    __bf16* wdl = wdh + 256 * 1024;                      // 0.25M
    __bf16* xdh = wdl + 256 * 1024;                      // 0.25M
    __bf16* xdl = xdh + 256 * 1024;                      // 0.25M (ends 25M floats)
    // big plane region [25M floats, ...)
    __bf16* planes = (__bf16*)(ws + 25 * M1);
    __bf16* xh  = planes;                    // 4M bf16
    __bf16* xl  = xh + 4 * M1;               // 4M
    __bf16* wih = xl + 4 * M1;               // 8M
    __bf16* wil = wih + 8 * M1;              // 8M
    // reuse (stream-ordered): xpart overlaps xh/xl (dead after GEMM1, consumed
    // by xdbl_reduce); yh/yl then overwrite the same region in scan_part3.
    __bf16* yh  = xh;
    __bf16* yl  = xl;
    float* xpart = (float*)planes;

    // 0) split all fp32 operands to bf16 hi/lo planes (one dispatch)
    split_all_kernel<<<2048, 256, 0, stream>>>(x, xh, xl, W_in, wih, wil,
                                               W_out, woh, wol, W_dt, wdh, wdl);

    // 1) xz = x @ W_in.T  (MFMA split-bf16)
    {
        dim3 grid(2 * D_MODEL / 128, BL / 128);
        gemm_bf3<0><<<grid, 256, 0, stream>>>(xh, xl, wih, wil, xz, nullptr,
                                              2 * D_MODEL, D_MODEL);
    }
    // 2) conv + silu (vectorized x4)
    conv_silu_kernel<<<BL * (D_MODEL / 4) / 256, 256, 0, stream>>>(xz, conv_w, conv_b, u);

    // 3) x_dbl = u @ W_xproj.T  (fp32 split-K; xpart overwrites dead x planes;
    //    reduce also emits dt_r bf16 planes)
    {
        dim3 grid(XPROJ_N / XBN, BL / XBM, XKS);
        xdbl_partial<<<grid, 256, 0, stream>>>(u, W_xproj, xpart);
        xdbl_reduce<<<(BL * XPROJ_N / 4 + 255) / 256, 256, 0, stream>>>(
            xpart, xdbl, xdh, xdl);
    }
    // 4) dt = softplus(dt_r @ W_dt.T + b_dt)  (MFMA split-bf16, K=128)
    {
        dim3 grid(D_MODEL / 128, BL / 128);
        gemm_bf3<1><<<grid, 256, 0, stream>>>(xdh, xdl, wdh, wdl, dt, b_dt,
                                              D_MODEL, DT_RANK);
    }
    // 5) chunked scan; S3 emits yh/yl bf16 planes directly (fused split)
    {
        dim3 grid(D_MODEL / 256, B_SZ * NC);
        scan_part1<<<grid, 256, 0, stream>>>(dt, xdbl, u, A_log, PH, Hend);
        scan_part2<<<B_SZ * D_MODEL * 16 / 256, 256, 0, stream>>>(PH, Hend);
        scan_part3<<<grid, 256, 0, stream>>>(dt, xdbl, xz, u, A_log, Dskip, PH, yh, yl);
    }
    // 6) out = yact @ W_out.T  (MFMA split-bf16)
    {
        dim3 grid(D_MODEL / 128, BL / 128);
        gemm_bf3<0><<<grid, 256, 0, stream>>>(yh, yl, woh, wol, out, nullptr,
                                              D_MODEL, D_MODEL);
    }
}

// Round 11
// 384.133 us; speedup vs baseline: 1.1042x; 1.0367x over previous
//
#include <hip/hip_runtime.h>
#include <hip/hip_bf16.h>

// Mamba block — compensated-f16 2-pass MFMA GEMMs + chunked scan.
//  0) split x,W_in,W_out,W_dt -> f16 (P1, P2-compensated) planes (ONE dispatch)
//  1) xz = x @ W_in.T      (2048x4096, K=2048)  MFMA f16-2pass   -> ws.xz (fp32)
//  2) u  = silu(conv4(xz[:, :2048]))            vectorized x4    -> ws.u
//  3) x_dbl = u @ W_xproj.T (2048x160, K=2048)  fp32 split-K(8); reduce also
//     emits f16 planes of x_dbl[:, :128]                         -> ws.xdbl,xd1/xd2
//  4) dt = softplus(dt_r @ W_dt.T + b_dt)       MFMA f16-2pass   -> ws.dt
//  5) chunked scan (S1/S2/S3), S3 emits y1/y2 f16 planes fused   -> ws.y1/y2
//  6) out = yact @ W_out.T (2048x2048, K=2048)  MFMA f16-2pass   -> d_out
//
// COMPENSATED 2-PASS SCHEME (replaces bf16 hi/lo 3-pass, round 11):
//   A1 = f16(A); A2 = f16(A1 + S*(A - A1)), S = 512 (same for W).
//   P1 = A1*W1, P2 = A2*W2 (2 MFMA passes, separate f32 accs).
//   C  = P1 + (P2 - P1)/S  =  AhWh + AhWl + AlWh + S*Al*Wl.
//   Residual error sigma ~ S*sqrt(K)*s(Al)*s(Wl) ~ 2e-5 << 1e-3 threshold.
//   Same staging bytes + ds_read count as 3-pass; 33% fewer MFMA.
//
// HISTORY (measured):
//  r6: BK=32 dbuf prefetch: REGRESSED (57->47 MfmaUtil) — drain just moved.
//  r8: 32x32x16: uniform 4/read bank conflict (slot bits can't spread 32 rows);
//      XCD swizzle: FETCH 82->139MB. Both reverted.
//  r10: 16x16x32, BK=64, both-sides XOR swizzle slot^=(row&7): 83.5us,
//      MfmaUtil 55%, 0 conflicts. Model: LDS-read ~1400cy + drain ~300cy vs
//      MFMA 930cy per K-tile per CU -> near LDS-BW bound; this round cuts the
//      MFMA term (930->620) to test whether it is additive or hidden.

#define D_MODEL 2048
#define D_STATE 16
#define KER 4
#define DT_RANK 128
#define B_SZ 2
#define SEQ 1024
#define BL (B_SZ * SEQ)
#define XPROJ_N (DT_RANK + 2 * D_STATE)  // 160
#define NC 32
#define TC (SEQ / NC)
#define CSCALE 512.0f
#define CINV (1.0f / 512.0f)

using f32x4  = __attribute__((ext_vector_type(4))) float;
using f16x8  = __attribute__((ext_vector_type(8))) _Float16;
using f16x4  = __attribute__((ext_vector_type(4))) _Float16;

__device__ __forceinline__ float softplusf(float x) {
    return (x > 20.f) ? x : log1pf(__expf(x));
}
__device__ __forceinline__ float siluf(float x) {
    return x / (1.f + __expf(-x));
}

// ---------------- fp32 -> (P1, P2) compensated f16 plane split ----------------
__device__ __forceinline__ void split4(const float* __restrict__ src,
                                       _Float16* __restrict__ p1,
                                       _Float16* __restrict__ p2, int i) {
    float4 v = *reinterpret_cast<const float4*>(&src[(size_t)i * 4]);
    f16x4 h1, h2;
    float f[4] = {v.x, v.y, v.z, v.w};
    #pragma unroll
    for (int j = 0; j < 4; ++j) {
        _Float16 h = (_Float16)f[j];
        float hf = (float)h;
        h1[j] = h;
        h2[j] = (_Float16)(fmaf(CSCALE, f[j] - hf, hf));
    }
    *reinterpret_cast<f16x4*>(&p1[(size_t)i * 4]) = h1;
    *reinterpret_cast<f16x4*>(&p2[(size_t)i * 4]) = h2;
}

// merged x + W_in + W_out + W_dt split (one dispatch), grid-stride.
__global__ __launch_bounds__(256) void split_all_kernel(
    const float* __restrict__ x,  _Float16* __restrict__ x1,  _Float16* __restrict__ x2,
    const float* __restrict__ wi, _Float16* __restrict__ wi1, _Float16* __restrict__ wi2,
    const float* __restrict__ wo, _Float16* __restrict__ wo1, _Float16* __restrict__ wo2,
    const float* __restrict__ wd, _Float16* __restrict__ wd1, _Float16* __restrict__ wd2)
{
    const int NX = BL * D_MODEL / 4;            // 1,048,576 float4s
    const int NI = 2 * D_MODEL * D_MODEL / 4;   // 2,097,152
    const int NO = D_MODEL * D_MODEL / 4;       // 1,048,576
    const int ND = D_MODEL * DT_RANK / 4;       // 65,536
    const int total = NX + NI + NO + ND;
    for (int i = blockIdx.x * 256 + threadIdx.x; i < total; i += gridDim.x * 256) {
        if      (i < NX)           split4(x,  x1,  x2,  i);
        else if (i < NX + NI)      split4(wi, wi1, wi2, i - NX);
        else if (i < NX + NI + NO) split4(wo, wo1, wo2, i - NX - NI);
        else                       split4(wd, wd1, wd2, i - NX - NI - NO);
    }
}

// ---------------- compensated-f16 2-pass MFMA NT GEMM ----------------
// C[m][n] = sum_k A[m,k]*W[n,k]; P1 = A1*W1, P2 = A2*W2, C = P1 + (P2-P1)/S.
// 128x128 tile, BK=64, 4 waves (2x2 of 64x64), mfma_f32_16x16x32_f16.
// LDS linear row-major [128][64] f16 per plane; XOR swizzle slot^=(row&7)
// applied on BOTH global source (pre-swizzle) and ds_read (rule #21).
// EPI: 0 = store raw, 1 = softplus(acc + bias[col]).
template <int EPI>
__global__ __launch_bounds__(256, 2) void gemm_f16c(
    const _Float16* __restrict__ A1, const _Float16* __restrict__ A2,
    const _Float16* __restrict__ W1, const _Float16* __restrict__ W2,
    float* __restrict__ C, const float* __restrict__ bias, int N_, int K)
{
    __shared__ __align__(16) _Float16 lds[4 * 128 * 64];
    _Float16* sA1 = lds;
    _Float16* sA2 = lds + 8192;
    _Float16* sW1 = lds + 16384;
    _Float16* sW2 = lds + 24576;

    const int tid = threadIdx.x;
    const int bm = blockIdx.y * 128;
    const int bn = blockIdx.x * 128;
    const int w  = tid >> 6;
    const int l  = tid & 63;
    const int wr = (w >> 1) * 64;
    const int wc = (w & 1) * 64;
    const int fr = l & 15;
    const int fq = l >> 4;

    f32x4 acc1[4][4] = {};
    f32x4 acc2[4][4] = {};

    for (int k0 = 0; k0 < K; k0 += 64) {
        #pragma unroll
        for (int i = 0; i < 4; ++i) {
            const int f  = i * 256 + tid;   // 16B chunk id 0..1023
            const int r  = f >> 3;          // tile row 0..127
            const int ss = f & 7;           // dest slot
            const int gs = ss ^ (r & 7);    // pre-swizzled source slot
            const size_t ga = (size_t)(bm + r) * K + k0 + gs * 8;
            const size_t gw = (size_t)(bn + r) * K + k0 + gs * 8;
            __builtin_amdgcn_global_load_lds(
                (const __attribute__((address_space(1))) void*)(A1 + ga),
                (__attribute__((address_space(3))) void*)(sA1 + (size_t)f * 8), 16, 0, 0);
            __builtin_amdgcn_global_load_lds(
                (const __attribute__((address_space(1))) void*)(A2 + ga),
                (__attribute__((address_space(3))) void*)(sA2 + (size_t)f * 8), 16, 0, 0);
            __builtin_amdgcn_global_load_lds(
                (const __attribute__((address_space(1))) void*)(W1 + gw),
                (__attribute__((address_space(3))) void*)(sW1 + (size_t)f * 8), 16, 0, 0);
            __builtin_amdgcn_global_load_lds(
                (const __attribute__((address_space(1))) void*)(W2 + gw),
                (__attribute__((address_space(3))) void*)(sW2 + (size_t)f * 8), 16, 0, 0);
        }
        __syncthreads();

        #pragma unroll
        for (int ks = 0; ks < 2; ++ks) {
            f16x8 a1[4], a2[4], w1[4], w2[4];
            #pragma unroll
            for (int t = 0; t < 4; ++t) {
                const int ra = wr + t * 16 + fr;
                const int sa = (ks * 4 + fq) ^ (ra & 7);
                a1[t] = *reinterpret_cast<const f16x8*>(&sA1[ra * 64 + sa * 8]);
                a2[t] = *reinterpret_cast<const f16x8*>(&sA2[ra * 64 + sa * 8]);
                const int rw = wc + t * 16 + fr;
                const int sw = (ks * 4 + fq) ^ (rw & 7);
                w1[t] = *reinterpret_cast<const f16x8*>(&sW1[rw * 64 + sw * 8]);
                w2[t] = *reinterpret_cast<const f16x8*>(&sW2[rw * 64 + sw * 8]);
            }
            #pragma unroll
            for (int mt = 0; mt < 4; ++mt)
                #pragma unroll
                for (int nt = 0; nt < 4; ++nt) {
                    acc1[mt][nt] = __builtin_amdgcn_mfma_f32_16x16x32_f16(
                        a1[mt], w1[nt], acc1[mt][nt], 0, 0, 0);
                    acc2[mt][nt] = __builtin_amdgcn_mfma_f32_16x16x32_f16(
                        a2[mt], w2[nt], acc2[mt][nt], 0, 0, 0);
                }
        }
        __syncthreads();
    }

    // C/D layout (m89-verified): col = lane&15, row = (lane>>4)*4 + reg
    #pragma unroll
    for (int mt = 0; mt < 4; ++mt)
        #pragma unroll
        for (int nt = 0; nt < 4; ++nt) {
            const int gn = bn + wc + nt * 16 + fr;
            #pragma unroll
            for (int j = 0; j < 4; ++j) {
                const float p1 = acc1[mt][nt][j];
                const float p2 = acc2[mt][nt][j];
                float v = fmaf(p2 - p1, CINV, p1);
                if (EPI == 1) v = softplusf(v + bias[gn]);
                C[(size_t)(bm + wr + mt * 16 + fq * 4 + j) * N_ + gn] = v;
            }
        }
}

// ---------------- split-K x_dbl GEMM: M=2048, N=160, K=2048 ----------------
#define BKT 32
#define XBM 64
#define XBN 32
#define XKS 8
#define XKC (D_MODEL / XKS)   // 256

__global__ __launch_bounds__(256) void xdbl_partial(
    const float* __restrict__ A,      // u (BL, D_MODEL)
    const float* __restrict__ W,      // W_xproj (160, D_MODEL)
    float* __restrict__ P)            // (XKS, BL, 160)
{
    __shared__ float As[BKT][XBM + 4];
    __shared__ float Ws[BKT][XBN + 4];

    const int tid = threadIdx.x;
    const int bm = blockIdx.y * XBM;
    const int bn = blockIdx.x * XBN;
    const int ks = blockIdx.z;
    const int tx = tid & 7;
    const int ty = tid >> 3;

    float acc[2][4] = {};

    const int kend = (ks + 1) * XKC;
    for (int k0 = ks * XKC; k0 < kend; k0 += BKT) {
        #pragma unroll
        for (int i = 0; i < 2; ++i) {
            int f = tid + i * 256;
            int row = f >> 3;
            int kq  = f & 7;
            float4 v = *reinterpret_cast<const float4*>(
                &A[(size_t)(bm + row) * D_MODEL + k0 + kq * 4]);
            As[kq * 4 + 0][row] = v.x;
            As[kq * 4 + 1][row] = v.y;
            As[kq * 4 + 2][row] = v.z;
            As[kq * 4 + 3][row] = v.w;
        }
        {
            int row = tid >> 3;
            int kq  = tid & 7;
            float4 v = *reinterpret_cast<const float4*>(
                &W[(size_t)(bn + row) * D_MODEL + k0 + kq * 4]);
            Ws[kq * 4 + 0][row] = v.x;
            Ws[kq * 4 + 1][row] = v.y;
            Ws[kq * 4 + 2][row] = v.z;
            Ws[kq * 4 + 3][row] = v.w;
        }
        __syncthreads();

        #pragma unroll
        for (int kk = 0; kk < BKT; ++kk) {
            float a0 = As[kk][ty * 2 + 0];
            float a1 = As[kk][ty * 2 + 1];
            float4 w4 = *reinterpret_cast<const float4*>(&Ws[kk][tx * 4]);
            float wv[4] = {w4.x, w4.y, w4.z, w4.w};
            #pragma unroll
            for (int j = 0; j < 4; ++j) {
                acc[0][j] = fmaf(a0, wv[j], acc[0][j]);
                acc[1][j] = fmaf(a1, wv[j], acc[1][j]);
            }
        }
        __syncthreads();
    }

    #pragma unroll
    for (int i = 0; i < 2; ++i) {
        const int gm = bm + ty * 2 + i;
        #pragma unroll
        for (int j = 0; j < 4; ++j) {
            const int gn = bn + tx * 4 + j;
            P[((size_t)ks * BL + gm) * XPROJ_N + gn] = acc[i][j];
        }
    }
}

// reduce 8 partials -> xdbl; also emit compensated-f16 planes of dt_r slice.
__global__ __launch_bounds__(256) void xdbl_reduce(
    const float* __restrict__ P, float* __restrict__ xdbl,
    _Float16* __restrict__ xd1, _Float16* __restrict__ xd2)
{
    const int i = blockIdx.x * 256 + threadIdx.x;
    const int n4 = BL * XPROJ_N / 4;
    if (i >= n4) return;
    float4 s = *reinterpret_cast<const float4*>(&P[(size_t)i * 4]);
    #pragma unroll
    for (int ks = 1; ks < XKS; ++ks) {
        float4 v = *reinterpret_cast<const float4*>(
            &P[(size_t)ks * BL * XPROJ_N + (size_t)i * 4]);
        s.x += v.x; s.y += v.y; s.z += v.z; s.w += v.w;
    }
    *reinterpret_cast<float4*>(&xdbl[(size_t)i * 4]) = s;

    const int row = i / (XPROJ_N / 4);          // = i / 40
    const int col = (i % (XPROJ_N / 4)) * 4;
    if (col < DT_RANK) {
        f16x4 h1, h2;
        float f[4] = {s.x, s.y, s.z, s.w};
        #pragma unroll
        for (int j = 0; j < 4; ++j) {
            _Float16 h = (_Float16)f[j];
            float hf = (float)h;
            h1[j] = h;
            h2[j] = (_Float16)(fmaf(CSCALE, f[j] - hf, hf));
        }
        *reinterpret_cast<f16x4*>(&xd1[(size_t)row * DT_RANK + col]) = h1;
        *reinterpret_cast<f16x4*>(&xd2[(size_t)row * DT_RANK + col]) = h2;
    }
}

// ------------- depthwise causal conv (K=4) + SiLU, 4 channels/thread -------------
__global__ __launch_bounds__(256) void conv_silu_kernel(
    const float* __restrict__ xz,      // (BL, 4096); u_raw = cols [0, 2048)
    const float* __restrict__ conv_w,  // (D, 4)
    const float* __restrict__ conv_b,  // (D,)
    float* __restrict__ u)             // (BL, D)
{
    int idx = blockIdx.x * 256 + threadIdx.x;      // over BL * D/4
    if (idx >= BL * (D_MODEL / 4)) return;
    const int d4 = (idx & (D_MODEL / 4 - 1)) * 4;
    const int bl = idx >> 9;                        // / (D/4)
    const int l  = bl & (SEQ - 1);
    const int b  = bl >> 10;

    float4 cb = *reinterpret_cast<const float4*>(&conv_b[d4]);
    float4 cw[4];
    #pragma unroll
    for (int j = 0; j < 4; ++j)
        cw[j] = *reinterpret_cast<const float4*>(&conv_w[(d4 + j) * KER]);

    float acc[4] = {cb.x, cb.y, cb.z, cb.w};
    #pragma unroll
    for (int k = 0; k < KER; ++k) {
        const int ls = l - (KER - 1) + k;
        if (ls >= 0) {
            float4 v = *reinterpret_cast<const float4*>(
                &xz[(size_t)(b * SEQ + ls) * (2 * D_MODEL) + d4]);
            acc[0] = fmaf((&cw[0].x)[k], v.x, acc[0]);
            acc[1] = fmaf((&cw[1].x)[k], v.y, acc[1]);
            acc[2] = fmaf((&cw[2].x)[k], v.z, acc[2]);
            acc[3] = fmaf((&cw[3].x)[k], v.w, acc[3]);
        }
    }
    float4 o;
    o.x = siluf(acc[0]); o.y = siluf(acc[1]);
    o.z = siluf(acc[2]); o.w = siluf(acc[3]);
    *reinterpret_cast<float4*>(&u[(size_t)bl * D_MODEL + d4]) = o;
}

// ---------------- chunked selective scan ----------------
__global__ __launch_bounds__(256) void scan_part1(
    const float* __restrict__ dt,
    const float* __restrict__ xdbl,
    const float* __restrict__ u,
    const float* __restrict__ A_log,
    float* __restrict__ PH,
    float* __restrict__ Hend)
{
    const int tid = threadIdx.x;
    const int d   = blockIdx.x * 256 + tid;
    const int bc  = blockIdx.y;
    const int b   = bc >> 5;
    const int c   = bc & (NC - 1);

    float A[16];
    #pragma unroll
    for (int q = 0; q < 4; ++q) {
        float4 v = *reinterpret_cast<const float4*>(&A_log[d * 16 + q * 4]);
        A[q*4+0] = -__expf(v.x); A[q*4+1] = -__expf(v.y);
        A[q*4+2] = -__expf(v.z); A[q*4+3] = -__expf(v.w);
    }
    float h[16] = {};
    float P[16];
    #pragma unroll
    for (int n = 0; n < 16; ++n) P[n] = 1.f;

    const size_t row0 = (size_t)b * SEQ + c * TC;
    for (int t = 0; t < TC; ++t) {
        const size_t row = row0 + t;
        const float dtv = dt[row * D_MODEL + d];
        const float uv  = u[row * D_MODEL + d];
        float Bv[16];
        const float4* Bp = reinterpret_cast<const float4*>(&xdbl[row * XPROJ_N + DT_RANK]);
        #pragma unroll
        for (int q = 0; q < 4; ++q) {
            float4 v = Bp[q];
            Bv[q*4+0] = v.x; Bv[q*4+1] = v.y; Bv[q*4+2] = v.z; Bv[q*4+3] = v.w;
        }
        const float dtu = dtv * uv;
        #pragma unroll
        for (int n = 0; n < 16; ++n) {
            float dA = __expf(dtv * A[n]);
            h[n] = fmaf(dA, h[n], dtu * Bv[n]);
            P[n] *= dA;
        }
    }
    const size_t off = ((size_t)bc * D_MODEL + d) * 16;
    #pragma unroll
    for (int q = 0; q < 4; ++q) {
        *reinterpret_cast<float4*>(&PH[off + q*4])   =
            make_float4(P[q*4+0], P[q*4+1], P[q*4+2], P[q*4+3]);
        *reinterpret_cast<float4*>(&Hend[off + q*4]) =
            make_float4(h[q*4+0], h[q*4+1], h[q*4+2], h[q*4+3]);
    }
}

__global__ __launch_bounds__(256) void scan_part2(
    float* __restrict__ PH,
    const float* __restrict__ Hend)
{
    const int g  = blockIdx.x * 256 + threadIdx.x;
    const int b  = g >> 15;
    const int dn = g & 32767;
    float h = 0.f;
    #pragma unroll
    for (int c = 0; c < NC; ++c) {
        const size_t off = ((size_t)(b * NC + c) * D_MODEL * 16) + dn;
        const float p  = PH[off];
        const float he = Hend[off];
        PH[off] = h;
        h = fmaf(p, h, he);
    }
}

// S3: replay each chunk from its true Hstart; emit gated output directly as
// compensated-f16 planes (fused split — feeds GEMM6).
__global__ __launch_bounds__(256) void scan_part3(
    const float* __restrict__ dt,
    const float* __restrict__ xdbl,
    const float* __restrict__ xz,
    const float* __restrict__ u,
    const float* __restrict__ A_log,
    const float* __restrict__ Dskip,
    const float* __restrict__ PH,
    _Float16* __restrict__ y1, _Float16* __restrict__ y2)
{
    const int tid = threadIdx.x;
    const int d   = blockIdx.x * 256 + tid;
    const int bc  = blockIdx.y;
    const int b   = bc >> 5;
    const int c   = bc & (NC - 1);

    float A[16];
    #pragma unroll
    for (int q = 0; q < 4; ++q) {
        float4 v = *reinterpret_cast<const float4*>(&A_log[d * 16 + q * 4]);
        A[q*4+0] = -__expf(v.x); A[q*4+1] = -__expf(v.y);
        A[q*4+2] = -__expf(v.z); A[q*4+3] = -__expf(v.w);
    }
    float h[16];
    const size_t off = ((size_t)bc * D_MODEL + d) * 16;
    #pragma unroll
    for (int q = 0; q < 4; ++q) {
        float4 v = *reinterpret_cast<const float4*>(&PH[off + q*4]);
        h[q*4+0] = v.x; h[q*4+1] = v.y; h[q*4+2] = v.z; h[q*4+3] = v.w;
    }
    const float Dk = Dskip[d];

    const size_t row0 = (size_t)b * SEQ + c * TC;
    for (int t = 0; t < TC; ++t) {
        const size_t row = row0 + t;
        const float dtv = dt[row * D_MODEL + d];
        const float uv  = u[row * D_MODEL + d];
        float Bv[16], Cv[16];
        const float4* Bp = reinterpret_cast<const float4*>(&xdbl[row * XPROJ_N + DT_RANK]);
        const float4* Cp = reinterpret_cast<const float4*>(&xdbl[row * XPROJ_N + DT_RANK + D_STATE]);
        #pragma unroll
        for (int q = 0; q < 4; ++q) {
            float4 v = Bp[q];
            Bv[q*4+0] = v.x; Bv[q*4+1] = v.y; Bv[q*4+2] = v.z; Bv[q*4+3] = v.w;
            float4 wv = Cp[q];
            Cv[q*4+0] = wv.x; Cv[q*4+1] = wv.y; Cv[q*4+2] = wv.z; Cv[q*4+3] = wv.w;
        }
        const float dtu = dtv * uv;
        float y = 0.f;
        #pragma unroll
        for (int n = 0; n < 16; ++n) {
            float dA = __expf(dtv * A[n]);
            h[n] = fmaf(dA, h[n], dtu * Bv[n]);
            y = fmaf(h[n], Cv[n], y);
        }
        const float zv = xz[row * (2 * D_MODEL) + D_MODEL + d];
        const float yv = (y + uv * Dk) * siluf(zv);
        const _Float16 hv = (_Float16)yv;
        const float hf = (float)hv;
        y1[row * D_MODEL + d] = hv;
        y2[row * D_MODEL + d] = (_Float16)(fmaf(CSCALE, yv - hf, hf));
    }
}

// ---------------- launch ----------------
extern "C" void kernel_launch(void* const* d_in, const int* in_sizes, int n_in,
                              void* d_out, int out_size, void* d_ws, size_t ws_size,
                              hipStream_t stream) {
    const float* x       = (const float*)d_in[0];
    const float* W_in    = (const float*)d_in[1];
    const float* conv_w  = (const float*)d_in[2];
    const float* conv_b  = (const float*)d_in[3];
    const float* W_xproj = (const float*)d_in[4];
    const float* W_dt    = (const float*)d_in[5];
    const float* b_dt    = (const float*)d_in[6];
    const float* A_log   = (const float*)d_in[7];
    const float* Dskip   = (const float*)d_in[8];
    const float* W_out   = (const float*)d_in[9];
    float* out = (float*)d_out;

    float* ws = (float*)d_ws;
    const size_t M1 = 1024 * 1024;
    // fp32 region [0, 20.5M floats)
    float* xz   = ws;                        // 8M fp32
    float* u    = ws + 8 * M1;               // 4M
    float* xdbl = ws + 12 * M1;              // 0.5M reserved
    float* dt   = ws + 12 * M1 + 512 * 1024; // 4M
    float* PH   = dt + 4 * M1;               // 2M
    float* Hend = PH + 2 * M1;               // 2M   (ends at 20.5M floats)
    // dedicated plane region [20.5M, 25M floats) = 18 MB:
    _Float16* wo1 = (_Float16*)(ws + 20 * M1 + 512 * 1024);  // 4M f16
    _Float16* wo2 = wo1 + 4 * M1;                            // 4M
    _Float16* wd1 = wo2 + 4 * M1;                            // 0.25M
    _Float16* wd2 = wd1 + 256 * 1024;                        // 0.25M
    _Float16* xd1 = wd2 + 256 * 1024;                        // 0.25M
    _Float16* xd2 = xd1 + 256 * 1024;                        // 0.25M (ends 25M)
    // big plane region [25M floats, ...)
    _Float16* planes = (_Float16*)(ws + 25 * M1);
    _Float16* x1  = planes;                  // 4M f16
    _Float16* x2  = x1 + 4 * M1;             // 4M
    _Float16* wi1 = x2 + 4 * M1;             // 8M
    _Float16* wi2 = wi1 + 8 * M1;            // 8M
    // reuse (stream-ordered): xpart overlaps x1/x2 (dead after GEMM1, consumed
    // by xdbl_reduce); y1/y2 then overwrite the same region in scan_part3.
    _Float16* y1 = x1;
    _Float16* y2 = x2;
    float* xpart = (float*)planes;

    // 0) split all fp32 operands to compensated-f16 planes (one dispatch)
    split_all_kernel<<<2048, 256, 0, stream>>>(x, x1, x2, W_in, wi1, wi2,
                                               W_out, wo1, wo2, W_dt, wd1, wd2);

    // 1) xz = x @ W_in.T  (MFMA f16-2pass)
    {
        dim3 grid(2 * D_MODEL / 128, BL / 128);
        gemm_f16c<0><<<grid, 256, 0, stream>>>(x1, x2, wi1, wi2, xz, nullptr,
                                               2 * D_MODEL, D_MODEL);
    }
    // 2) conv + silu (vectorized x4)
    conv_silu_kernel<<<BL * (D_MODEL / 4) / 256, 256, 0, stream>>>(xz, conv_w, conv_b, u);

    // 3) x_dbl = u @ W_xproj.T  (fp32 split-K; xpart overwrites dead x planes;
    //    reduce also emits dt_r f16 planes)
    {
        dim3 grid(XPROJ_N / XBN, BL / XBM, XKS);
        xdbl_partial<<<grid, 256, 0, stream>>>(u, W_xproj, xpart);
        xdbl_reduce<<<(BL * XPROJ_N / 4 + 255) / 256, 256, 0, stream>>>(
            xpart, xdbl, xd1, xd2);
    }
    // 4) dt = softplus(dt_r @ W_dt.T + b_dt)  (MFMA f16-2pass, K=128)
    {
        dim3 grid(D_MODEL / 128, BL / 128);
        gemm_f16c<1><<<grid, 256, 0, stream>>>(xd1, xd2, wd1, wd2, dt, b_dt,
                                               D_MODEL, DT_RANK);
    }
    // 5) chunked scan; S3 emits y1/y2 f16 planes directly (fused split)
    {
        dim3 grid(D_MODEL / 256, B_SZ * NC);
        scan_part1<<<grid, 256, 0, stream>>>(dt, xdbl, u, A_log, PH, Hend);
        scan_part2<<<B_SZ * D_MODEL * 16 / 256, 256, 0, stream>>>(PH, Hend);
        scan_part3<<<grid, 256, 0, stream>>>(dt, xdbl, xz, u, A_log, Dskip, PH, y1, y2);
    }
    // 6) out = yact @ W_out.T  (MFMA f16-2pass)
    {
        dim3 grid(D_MODEL / 128, BL / 128);
        gemm_f16c<0><<<grid, 256, 0, stream>>>(y1, y2, wo1, wo2, out, nullptr,
                                               D_MODEL, D_MODEL);
    }
}